// Round 7
// baseline (127.022 us; speedup 1.0000x reference)
//
#include <hip/hip_runtime.h>
#include <hip/hip_bf16.h>

// Problem constants
#define BB 16
#define SS 1024
#define DD 384
#define HH 6
#define KK 9
#define KH 54      // K*H
#define OUTD 384
#define NKT 12     // K-steps: 384/32
#define VLD 392    // LDS leading dim (bf16): 784 B/row -> 4-bank shift/row, <=2-way (free)

typedef __attribute__((ext_vector_type(4))) float floatx4;
typedef __attribute__((ext_vector_type(8))) __bf16 bf16x8;
typedef __attribute__((ext_vector_type(4))) __bf16 bf16x4;

// ---------------------------------------------------------------------------
// Kernel 0: cast + swizzle weights into MFMA B-fragment order.
// WkT: 4 ntiles (54 rows zero-padded to 64) x 12 ksteps x 64 lanes x 8 bf16.
// WpT: 24 ntiles x 12 ksteps x 64 lanes x 8 bf16.
// Fragment: lane = n_in_tile(0..15) + 16*k_quad; elems = 8 consecutive k.
// Every MFMA B-load is ONE lane-contiguous 1-KB transaction (L2-resident).
// ---------------------------------------------------------------------------
__global__ __launch_bounds__(256) void cast_kernel(const float* __restrict__ Wk,
                                                   const float* __restrict__ Wp,
                                                   __bf16* __restrict__ WkT,
                                                   __bf16* __restrict__ WpT) {
    int i = blockIdx.x * 256 + threadIdx.x;
    if (i < 4 * NKT * 64 * 8) {                    // 24576 elems of WkT
        int e = i & 7, lane = (i >> 3) & 63, t = i >> 9;
        int kstep = t % NKT, ntile = t / NKT;
        int row = ntile * 16 + (lane & 15);
        int col = kstep * 32 + ((lane >> 4) << 3) + e;
        WkT[i] = (row < KH) ? (__bf16)Wk[row * DD + col] : (__bf16)0.0f;
    } else if (i < 24576 + 24 * NKT * 64 * 8) {    // 147456 elems of WpT
        int j = i - 24576;
        int e = j & 7, lane = (j >> 3) & 63, t = j >> 9;
        int kstep = t % NKT, ntile = t / NKT;
        int row = ntile * 16 + (lane & 15);
        int col = kstep * 32 + ((lane >> 4) << 3) + e;
        WpT[j] = (__bf16)Wp[row * DD + col];
    }
}

// ---------------------------------------------------------------------------
// Kernel 1: FULLY fused, front-loaded loads. Block = 16 seq rows, grid 1024.
// Phase 0 stages qk (arena rows 0..15) AND the v window (arena rows 16..39)
// together: ~30 independent global dwordx4 per thread in flight at kernel
// start (single memory epoch). A-tile overlays the dead qk region after B2.
// LDS = 31360 (arena) + 3584 (dk) + 4224 (lg) = 39168 B -> 4 blocks/CU,
// all 1024 blocks co-resident (16 waves/CU). Weights read ONCE per block.
// ---------------------------------------------------------------------------
__global__ __launch_bounds__(256, 4) void fused_kernel(const float* __restrict__ q,
                                                       const float* __restrict__ ks,
                                                       const float* __restrict__ v,
                                                       const __bf16* __restrict__ WkT,
                                                       const float* __restrict__ bk,
                                                       const __bf16* __restrict__ WpT,
                                                       const float* __restrict__ bp,
                                                       float* __restrict__ out) {
    __shared__ __bf16 vqS[40 * VLD];   // rows 0..15: qk (later A-tile); 16..39: v window
    __shared__ float  dkS[16 * 56];    // 3584 B softmaxed taps
    __shared__ float  lgS[16 * 66];    // 4224 B logits

    const int tid  = threadIdx.x;
    const int wave = tid >> 6;
    const int lane = tid & 63;
    const int m0   = blockIdx.x * 16;
    const int b    = blockIdx.x >> 6;                  // 64 blocks per batch
    const int s0   = (blockIdx.x & 63) * 16;
    const int fr   = lane & 15;
    const int fk   = (lane >> 4) * 8;
    const int col_in = lane & 15;
    const int rgrp   = (lane >> 4) * 4;

    __bf16* aS = &vqS[0];              // A-tile overlays qk region after B2

    // ---- phase 0: stage qk (rows 0..15) AND v window (rows 16..39) ----
    {
        const float* qb = q  + (size_t)m0 * DD;
        const float* kb = ks + (size_t)m0 * DD;
#pragma unroll
        for (int it = 0; it < 6; ++it) {
            int c = tid + it * 256;                    // 0..1535 float4-chunks
            int row = c / 96, col = (c % 96) * 4;
            floatx4 qv = *reinterpret_cast<const floatx4*>(qb + (size_t)row * DD + col);
            floatx4 kv = *reinterpret_cast<const floatx4*>(kb + (size_t)row * DD + col);
            floatx4 pr = qv * kv;
            bf16x4 pk = { (__bf16)pr.x, (__bf16)pr.y, (__bf16)pr.z, (__bf16)pr.w };
            *reinterpret_cast<bf16x4*>(&vqS[row * VLD + col]) = pk;
        }
        const float* vb = v + (size_t)b * SS * DD;
        if (s0 != 0 && s0 != SS - 16) {
#pragma unroll
            for (int it = 0; it < 9; ++it) {
                int c = tid + it * 256;                // 0..2303 float4-chunks
                int row = c / 96, col = (c % 96) * 4;
                floatx4 val = *reinterpret_cast<const floatx4*>(
                    vb + (size_t)(s0 + row - 4) * DD + col);
                bf16x4 vk = { (__bf16)val.x, (__bf16)val.y, (__bf16)val.z, (__bf16)val.w };
                *reinterpret_cast<bf16x4*>(&vqS[(16 + row) * VLD + col]) = vk;
            }
        } else {
#pragma unroll
            for (int it = 0; it < 9; ++it) {
                int c = tid + it * 256;
                int row = c / 96, col = (c % 96) * 4;
                int r = s0 + row - 4;
                floatx4 val = {};
                if (r >= 0 && r < SS)
                    val = *reinterpret_cast<const floatx4*>(vb + (size_t)r * DD + col);
                bf16x4 vk = { (__bf16)val.x, (__bf16)val.y, (__bf16)val.z, (__bf16)val.w };
                *reinterpret_cast<bf16x4*>(&vqS[(16 + row) * VLD + col]) = vk;
            }
        }
    }
    __syncthreads();   // B1

    // ---- phase 2: logits MFMA. wave = ntile (full K, WkT read once/block) ----
    {
        floatx4 acc = {};
#pragma unroll
        for (int s = 0; s < NKT; ++s) {
            bf16x8 af = *reinterpret_cast<const bf16x8*>(&vqS[fr * VLD + s * 32 + fk]);
            bf16x8 bf = *reinterpret_cast<const bf16x8*>(
                WkT + (((wave * NKT + s) * 64 + lane) << 3));
            acc = __builtin_amdgcn_mfma_f32_16x16x32_bf16(af, bf, acc, 0, 0, 0);
        }
        // C/D layout: col = lane&15, row = (lane>>4)*4 + reg
#pragma unroll
        for (int r = 0; r < 4; ++r)
            lgS[(rgrp + r) * 66 + wave * 16 + col_in] = acc[r];
    }
    __syncthreads();   // B2 (all qk reads done -> aS overlay now safe)

    // ---- phase 3a: softmax over 9 taps (96 tasks) -> dkS ----
    if (tid < 16 * HH) {
        int row = tid / HH, h = tid % HH;
        float lg[KK];
        float mx = -1e30f;
#pragma unroll
        for (int k = 0; k < KK; ++k) {
            float s = lgS[row * 66 + h * KK + k] + bk[h * KK + k];
            lg[k] = s;
            mx = fmaxf(mx, s);
        }
        float sum = 0.0f;
#pragma unroll
        for (int k = 0; k < KK; ++k) { lg[k] = __expf(lg[k] - mx); sum += lg[k]; }
        float inv = 1.0f / sum;
#pragma unroll
        for (int k = 0; k < KK; ++k) dkS[row * 56 + h * KK + k] = lg[k] * inv;
    }
    __syncthreads();   // B3

    // ---- phase 4: 9-tap conv from LDS v-window -> A-tile (overlays qk) ----
#pragma unroll
    for (int it = 0; it < 6; ++it) {
        int p = tid + it * 256;                        // 0..1535
        int row = p / 96, c4 = p % 96;
        int h = c4 >> 4;
        const float* dkr = &dkS[row * 56 + h * KK];
        floatx4 a = {};
#pragma unroll
        for (int k = 0; k < KK; ++k) {
            bf16x4 w = *reinterpret_cast<const bf16x4*>(&vqS[(16 + row + k) * VLD + c4 * 4]);
            floatx4 wf = { (float)w[0], (float)w[1], (float)w[2], (float)w[3] };
            a += wf * dkr[k];
        }
        bf16x4 o = { (__bf16)a.x, (__bf16)a.y, (__bf16)a.z, (__bf16)a.w };
        *reinterpret_cast<bf16x4*>(&aS[row * VLD + c4 * 4]) = o;
    }
    __syncthreads();   // B4

    // ---- phase 5: C = A @ Wp^T + bp. wave = col-quarter (6 ntiles), M=16.
    //      WpT read ONCE per block; A-frags via ds_read_b128.
    {
        const int nt0 = wave * 6;
        floatx4 acc[6] = {};
#pragma unroll
        for (int s = 0; s < NKT; ++s) {
            bf16x8 af = *reinterpret_cast<const bf16x8*>(&aS[fr * VLD + s * 32 + fk]);
#pragma unroll
            for (int j = 0; j < 6; ++j) {
                bf16x8 bf = *reinterpret_cast<const bf16x8*>(
                    WpT + ((((nt0 + j) * NKT + s) * 64 + lane) << 3));
                acc[j] = __builtin_amdgcn_mfma_f32_16x16x32_bf16(af, bf, acc[j], 0, 0, 0);
            }
        }
        float* ob = out + (size_t)m0 * OUTD;
#pragma unroll
        for (int j = 0; j < 6; ++j) {
            int col = (nt0 + j) * 16 + col_in;
            float bv = bp[col];
#pragma unroll
            for (int r = 0; r < 4; ++r)
                ob[(size_t)(rgrp + r) * OUTD + col] = acc[j][r] + bv;
        }
    }
}

// ---------------------------------------------------------------------------
extern "C" void kernel_launch(void* const* d_in, const int* in_sizes, int n_in,
                              void* d_out, int out_size, void* d_ws, size_t ws_size,
                              hipStream_t stream) {
    const float* q  = (const float*)d_in[0];
    const float* ks = (const float*)d_in[1];
    const float* v  = (const float*)d_in[2];
    const float* Wk = (const float*)d_in[3];
    const float* bk = (const float*)d_in[4];
    const float* Wp = (const float*)d_in[5];
    const float* bp = (const float*)d_in[6];
    float* out = (float*)d_out;

    // ws layout: WkT bf16 49152 B | WpT bf16 294912 B
    __bf16* WkT = (__bf16*)d_ws;
    __bf16* WpT = (__bf16*)((char*)d_ws + 49152);

    cast_kernel<<<(24576 + 147456 + 255) / 256, 256, 0, stream>>>(Wk, Wp, WkT, WpT);
    fused_kernel<<<(BB * SS) / 16, 256, 0, stream>>>(q, ks, v, WkT, bk, WpT, bp, out);
}